// Round 10
// baseline (1954.685 us; speedup 1.0000x reference)
//
#include <hip/hip_runtime.h>
#include <hip/hip_bf16.h>

#define TOK 100352      // B*H*W = 32*56*56
#define CC  128

// ---------------------------------------------------------------------------
// LayerNorm, one wave (64 lanes) per token, 4 tokens per 256-thread block.
// windowed=1: read natural layout (global xin) with shift-roll at global token
//             token0+t, write chunk-local windowed layout.
// windowed=0: chunk-local natural -> chunk-local natural.
// ---------------------------------------------------------------------------
__global__ __launch_bounds__(256) void ln_kernel(
    const float* __restrict__ xin, const float* __restrict__ g,
    const float* __restrict__ bta, float* __restrict__ out,
    int shift, int windowed, int token0)
{
    int t = blockIdx.x * 4 + (threadIdx.x >> 6);   // chunk-local token
    int lane  = threadIdx.x & 63;
    size_t src;
    if (windowed) {
        int tg = token0 + t;
        int b = tg / 3136;
        int r = tg - b * 3136;
        int win = r / 49, n = r - win * 49;
        int wh = win >> 3, ww = win & 7;
        int y = wh * 7 + n / 7, x = ww * 7 + (n % 7);
        int sy = (y + shift) % 56, sx = (x + shift) % 56;
        src = (size_t)(b * 3136 + sy * 56 + sx);
    } else {
        src = (size_t)t;
    }
    const float* xp = xin + src * CC;
    float a0 = xp[lane], a1 = xp[lane + 64];
    float s = a0 + a1, ss = a0 * a0 + a1 * a1;
#pragma unroll
    for (int off = 32; off; off >>= 1) {
        s  += __shfl_xor(s, off, 64);
        ss += __shfl_xor(ss, off, 64);
    }
    float mu  = s * (1.f / 128.f);
    float var = ss * (1.f / 128.f) - mu * mu;
    float rs  = rsqrtf(var + 1e-5f);
    float* op = out + (size_t)t * CC;
    op[lane]      = (a0 - mu) * rs * g[lane]      + bta[lane];
    op[lane + 64] = (a1 - mu) * rs * g[lane + 64] + bta[lane + 64];
}

// ---------------------------------------------------------------------------
// f32 tiled GEMM: C[Mc,N] = A[Mc,K] @ B[K,N] + bias, 64x64 tile, 4x4/thr
// EPI: 0 = plain store (qkv)
//      1 = proj: window-reverse + roll-back + residual add; A rows are
//          chunk-local windowed tokens, global row = rowOffs + r; resid is
//          GLOBAL natural-layout pointer, Cout is CHUNK-LOCAL natural.
//      2 = exact GELU (ffn1)
//      3 = residual add (ffn2): resid chunk-local, Cout chunk-local (caller
//          offsets the global output pointer by the chunk base).
// ---------------------------------------------------------------------------
template<int EPI>
__global__ __launch_bounds__(256) void gemm64(
    const float* __restrict__ A, const float* __restrict__ Bw,
    const float* __restrict__ bias, float* __restrict__ Cout,
    const float* __restrict__ resid, int N, int K, int shift, int rowOffs)
{
    __shared__ float As[16][68];
    __shared__ float Bs[16][68];
    int tid = threadIdx.x;
    int ty = tid >> 4, tx = tid & 15;
    int row0 = blockIdx.x * 64, col0 = blockIdx.y * 64;

    float acc[4][4] = {};

    int am = tid >> 2, ak = (tid & 3) * 4;    // A loader
    int bk = tid >> 4, bn = (tid & 15) * 4;   // B loader
    const float* Aptr = A + (size_t)(row0 + am) * K + ak;
    const float* Bptr = Bw + (size_t)bk * N + col0 + bn;

    for (int kt = 0; kt < K; kt += 16) {
        float4 av = *(const float4*)(Aptr + kt);
        float4 bv = *(const float4*)(Bptr + (size_t)kt * N);
        As[ak + 0][am] = av.x;
        As[ak + 1][am] = av.y;
        As[ak + 2][am] = av.z;
        As[ak + 3][am] = av.w;
        *(float4*)&Bs[bk][bn] = bv;
        __syncthreads();
#pragma unroll
        for (int kk = 0; kk < 16; ++kk) {
            const float4 a4 = *(const float4*)&As[kk][ty * 4];
            const float4 b4 = *(const float4*)&Bs[kk][tx * 4];
            const float aa[4] = {a4.x, a4.y, a4.z, a4.w};
            const float bb[4] = {b4.x, b4.y, b4.z, b4.w};
#pragma unroll
            for (int i = 0; i < 4; ++i)
#pragma unroll
                for (int j = 0; j < 4; ++j)
                    acc[i][j] += aa[i] * bb[j];
        }
        __syncthreads();
    }

#pragma unroll
    for (int i = 0; i < 4; ++i) {
        int r = row0 + ty * 4 + i;             // chunk-local row
        size_t dglob = 0, dloc = 0;
        if (EPI == 1) {
            int rg = rowOffs + r;
            int b = rg / 3136;
            int t = rg - b * 3136;
            int win = t / 49, n = t - win * 49;
            int wh = win >> 3, ww = win & 7;
            int y = wh * 7 + n / 7, x = ww * 7 + (n % 7);
            int yy = (y + shift) % 56, xx = (x + shift) % 56;
            dglob = (size_t)(b * 3136 + yy * 56 + xx);
            dloc  = dglob - (size_t)rowOffs;
        }
#pragma unroll
        for (int j = 0; j < 4; ++j) {
            int c = col0 + tx * 4 + j;
            float v = acc[i][j] + bias[c];
            if (EPI == 0) {
                Cout[(size_t)r * N + c] = v;
            } else if (EPI == 1) {
                Cout[dloc * CC + c] = resid[dglob * CC + c] + v;
            } else if (EPI == 2) {
                Cout[(size_t)r * N + c] = 0.5f * v * (1.f + erff(v * 0.70710678118654752f));
            } else {
                Cout[(size_t)r * CC + c] = resid[(size_t)r * CC + c] + v;
            }
        }
    }
}

// ---------------------------------------------------------------------------
// Attention: one block per (window, head), chunk-local. N=49 tokens, HD=32.
// qkv layout per row: [0:128)=q (h*32+d), [128:256)=k, [256:384)=v
// Window geometry depends only on win % 64 (windows/image), so chunk-local
// indices work as long as chunks are whole images.
// ---------------------------------------------------------------------------
__global__ __launch_bounds__(256) void attn_kernel(
    const float* __restrict__ qkv, const float* __restrict__ rpb,
    float* __restrict__ out, int shifted)
{
    __shared__ float qs[49 * 33];
    __shared__ float ks[49 * 33];
    __shared__ float vs[49 * 33];
    __shared__ float Ss[49 * 50];

    int win = blockIdx.x >> 2;
    int h   = blockIdx.x & 3;
    int tid = threadIdx.x;
    int whh = (win & 63) >> 3, www = win & 7;

    for (int idx = tid; idx < 49 * 32; idx += 256) {
        int n = idx >> 5, d = idx & 31;
        size_t base = (size_t)(win * 49 + n) * 384 + h * 32 + d;
        qs[n * 33 + d] = qkv[base] * 0.17677669529663687f;  // HD^-0.5
        ks[n * 33 + d] = qkv[base + 128];
        vs[n * 33 + d] = qkv[base + 256];
    }
    __syncthreads();

    for (int idx = tid; idx < 49 * 49; idx += 256) {
        int i = idx / 49, j = idx - i * 49;
        float s = 0.f;
#pragma unroll 8
        for (int d = 0; d < 32; ++d) s += qs[i * 33 + d] * ks[j * 33 + d];
        int ih = i / 7, iw = i - ih * 7, jh = j / 7, jw = j - jh * 7;
        int ridx = (ih - jh + 6) * 13 + (iw - jw + 6);
        s += rpb[ridx * 4 + h];
        if (shifted) {
            int yi = whh * 7 + ih, xi = www * 7 + iw;
            int yj = whh * 7 + jh, xj = www * 7 + jw;
            int ci = (yi < 49 ? 0 : (yi < 53 ? 1 : 2)) * 3 + (xi < 49 ? 0 : (xi < 53 ? 1 : 2));
            int cj = (yj < 49 ? 0 : (yj < 53 ? 1 : 2)) * 3 + (xj < 49 ? 0 : (xj < 53 ? 1 : 2));
            if (ci != cj) s -= 100.f;
        }
        Ss[i * 50 + j] = s;
    }
    __syncthreads();

    if (tid < 49) {
        float m = -1e30f;
        for (int j = 0; j < 49; ++j) m = fmaxf(m, Ss[tid * 50 + j]);
        float sum = 0.f;
        for (int j = 0; j < 49; ++j) {
            float e = expf(Ss[tid * 50 + j] - m);
            Ss[tid * 50 + j] = e;
            sum += e;
        }
        float inv = 1.f / sum;
        for (int j = 0; j < 49; ++j) Ss[tid * 50 + j] *= inv;
    }
    __syncthreads();

    for (int idx = tid; idx < 49 * 32; idx += 256) {
        int i = idx >> 5, d = idx & 31;
        float s = 0.f;
#pragma unroll 7
        for (int j = 0; j < 49; ++j) s += Ss[i * 50 + j] * vs[j * 33 + d];
        out[(size_t)(win * 49 + i) * CC + h * 32 + d] = s;
    }
}

// ---------------------------------------------------------------------------
extern "C" void kernel_launch(void* const* d_in, const int* in_sizes, int n_in,
                              void* d_out, int out_size, void* d_ws, size_t ws_size,
                              hipStream_t stream)
{
    const float* x    = (const float*)d_in[0];
    const float* n1g  = (const float*)d_in[1];
    const float* n1b  = (const float*)d_in[2];
    const float* qkvw = (const float*)d_in[3];
    const float* qkvb = (const float*)d_in[4];
    const float* rpb  = (const float*)d_in[5];
    const float* pw   = (const float*)d_in[6];
    const float* pb   = (const float*)d_in[7];
    const float* n2g  = (const float*)d_in[8];
    const float* n2b  = (const float*)d_in[9];
    const float* f1w  = (const float*)d_in[10];
    const float* f1b  = (const float*)d_in[11];
    const float* f2w  = (const float*)d_in[12];
    const float* f2b  = (const float*)d_in[13];
    float* out = (float*)d_out;

    // Pick images-per-chunk so chunk buffers PROVABLY fit in ws_size.
    // Per-image bytes: 3136 tokens * (128 + 512 + 128) floats = 9,633,792 B.
    // ws_size is constant across calls => identical launch sequence (capture-safe).
    const size_t PER_IMG = (size_t)3136 * 3072;
    int ipc = 1;
    for (int cand = 8; cand >= 1; cand >>= 1) {
        if ((size_t)cand * PER_IMG <= ws_size) { ipc = cand; break; }
    }
    const int MCd    = ipc * 3136;        // rows (tokens) per chunk
    const int nchunk = 32 / ipc;          // chunks over the batch

    char* ws = (char*)d_ws;
    const size_t SZ_C   = (size_t)MCd * CC * 4;
    const size_t SZ_BIG = (size_t)MCd * 512 * 4;
    float* bufA = (float*)ws;                      // xw -> attn_out -> ln2 (serial reuse)
    float* big  = (float*)(ws + SZ_C);             // qkv (Mc x 384), then ffn hidden (Mc x 512)
    float* x1c  = (float*)(ws + SZ_C + SZ_BIG);    // post-attn residual, chunk-local

    const float* xin = x;
    for (int i = 0; i < 2; ++i) {
        int shift = i ? 3 : 0;
        float* xout = out;   // block 0 writes d_out as intermediate; block 1 overwrites

        for (int c = 0; c < nchunk; ++c) {
            int R0 = c * MCd;
            // LN1 + shift + window partition (global read, chunk-local write)
            ln_kernel<<<MCd / 4, 256, 0, stream>>>(xin, n1g + i * 128, n1b + i * 128,
                                                   bufA, shift, 1, R0);
            // QKV projection (chunk-local)
            {
                dim3 g(MCd / 64, 6);
                gemm64<0><<<g, 256, 0, stream>>>(bufA, qkvw + i * 49152, qkvb + i * 384,
                                                 big, nullptr, 384, 128, 0, 0);
            }
            // attention (chunk-local windows; geometry from win % 64)
            attn_kernel<<<(MCd / 49) * 4, 256, 0, stream>>>(big, rpb + i * 676, bufA, i);
            // proj + window-reverse + un-roll + residual add -> x1c (chunk natural)
            {
                dim3 g(MCd / 64, 2);
                gemm64<1><<<g, 256, 0, stream>>>(bufA, pw + i * 16384, pb + i * 128,
                                                 x1c, xin, 128, 128, shift, R0);
            }
            // LN2 (chunk-local)
            ln_kernel<<<MCd / 4, 256, 0, stream>>>(x1c, n2g + i * 128, n2b + i * 128,
                                                   bufA, 0, 0, 0);
            // FFN1 + GELU (chunk-local)
            {
                dim3 g(MCd / 64, 8);
                gemm64<2><<<g, 256, 0, stream>>>(bufA, f1w + i * 65536, f1b + i * 512,
                                                 big, nullptr, 512, 128, 0, 0);
            }
            // FFN2 + residual -> xout rows [R0, R0+MCd)
            {
                dim3 g(MCd / 64, 2);
                gemm64<3><<<g, 256, 0, stream>>>(big, f2w + i * 65536, f2b + i * 128,
                                                 xout + (size_t)R0 * CC, x1c, 128, 512, 0, 0);
            }
        }
        xin = xout;
    }
    (void)in_sizes; (void)n_in; (void)out_size;
}

// Round 12
// 1388.167 us; speedup vs baseline: 1.4081x; 1.4081x over previous
//
#include <hip/hip_runtime.h>
#include <hip/hip_bf16.h>
#include <stdint.h>

#define CC 128

typedef __attribute__((ext_vector_type(8))) short short8;
typedef __attribute__((ext_vector_type(4))) float f32x4;
typedef __hip_bfloat16 bf16;

__device__ __forceinline__ float bf2f(short s) {
    union { unsigned u; float f; } cv;
    cv.u = ((unsigned)(unsigned short)s) << 16;
    return cv.f;
}

// ---------------------------------------------------------------------------
// Weight prep: W[K][N] f32 -> WT[N][K] bf16 (coalesced writes, tiny op)
// ---------------------------------------------------------------------------
__global__ __launch_bounds__(256) void transposeW(
    const float* __restrict__ W, bf16* __restrict__ WT, int K, int N)
{
    int idx = blockIdx.x * 256 + threadIdx.x;
    if (idx >= K * N) return;
    int n = idx / K, k = idx - n * K;
    WT[idx] = __float2bfloat16(W[(size_t)k * N + n]);
}

// ---------------------------------------------------------------------------
// LN1: natural f32 (global, shift-roll read) -> windowed chunk-local bf16
// ---------------------------------------------------------------------------
__global__ __launch_bounds__(256) void ln1_kernel(
    const float* __restrict__ xin, const float* __restrict__ g,
    const float* __restrict__ bta, bf16* __restrict__ out,
    int shift, int token0)
{
    int t = blockIdx.x * 4 + (threadIdx.x >> 6);   // chunk-local windowed token
    int lane = threadIdx.x & 63;
    int tg = token0 + t;
    int b = tg / 3136, r = tg - b * 3136;
    int win = r / 49, n = r - win * 49;
    int wh = win >> 3, ww = win & 7;
    int y = wh * 7 + n / 7, x = ww * 7 + (n % 7);
    int sy = (y + shift) % 56, sx = (x + shift) % 56;
    const float* xp = xin + (size_t)(b * 3136 + sy * 56 + sx) * CC;
    float a0 = xp[lane], a1 = xp[lane + 64];
    float s = a0 + a1, ss = a0 * a0 + a1 * a1;
#pragma unroll
    for (int off = 32; off; off >>= 1) {
        s  += __shfl_xor(s, off, 64);
        ss += __shfl_xor(ss, off, 64);
    }
    float mu = s * (1.f / 128.f);
    float var = ss * (1.f / 128.f) - mu * mu;
    float rs = rsqrtf(var + 1e-5f);
    bf16* op = out + (size_t)t * CC;
    op[lane]      = __float2bfloat16((a0 - mu) * rs * g[lane]      + bta[lane]);
    op[lane + 64] = __float2bfloat16((a1 - mu) * rs * g[lane + 64] + bta[lane + 64]);
}

// ---------------------------------------------------------------------------
// ln2_fused: x1 = xin(natural f32, global) + proj(windowed bf16, inverse-map);
// writes x1c (f32 natural chunk-local) AND LN2 output (bf16 natural chunk-local)
// ---------------------------------------------------------------------------
__global__ __launch_bounds__(256) void ln2_fused(
    const bf16* __restrict__ projw, const float* __restrict__ xin,
    const float* __restrict__ g, const float* __restrict__ bta,
    float* __restrict__ x1c, bf16* __restrict__ lnout,
    int shift, int token0)
{
    int t = blockIdx.x * 4 + (threadIdx.x >> 6);   // chunk-local natural token
    int lane = threadIdx.x & 63;
    int tg = token0 + t;
    int r = tg % 3136;
    int Y = r / 56, X = r - Y * 56;
    int y = (Y + 56 - shift) % 56, x = (X + 56 - shift) % 56;
    int win = (y / 7) * 8 + (x / 7);
    int n = (y % 7) * 7 + (x % 7);
    int bl = t / 3136;                              // chunk-local image index
    size_t wtok = (size_t)(bl * 64 + win) * 49 + n; // chunk-local windowed token
    const bf16* pp = projw + wtok * CC;
    float a0 = xin[(size_t)tg * CC + lane]      + __bfloat162float(pp[lane]);
    float a1 = xin[(size_t)tg * CC + lane + 64] + __bfloat162float(pp[lane + 64]);
    float* xp = x1c + (size_t)t * CC;
    xp[lane] = a0; xp[lane + 64] = a1;
    float s = a0 + a1, ss = a0 * a0 + a1 * a1;
#pragma unroll
    for (int off = 32; off; off >>= 1) {
        s  += __shfl_xor(s, off, 64);
        ss += __shfl_xor(ss, off, 64);
    }
    float mu = s * (1.f / 128.f);
    float var = ss * (1.f / 128.f) - mu * mu;
    float rs = rsqrtf(var + 1e-5f);
    bf16* op = lnout + (size_t)t * CC;
    op[lane]      = __float2bfloat16((a0 - mu) * rs * g[lane]      + bta[lane]);
    op[lane + 64] = __float2bfloat16((a1 - mu) * rs * g[lane + 64] + bta[lane + 64]);
}

// ---------------------------------------------------------------------------
// MFMA GEMM: C[Mrows,N] = A[Mrows,K](bf16) @ WT[N,K]^T(bf16) + bias
// 128x128 tile, 4 waves (2x2 of 64x64), 16x16x32 bf16 MFMA, BK=32.
// LDS layout [k-chunk(4)][row(128)][8 bf16]: 16-lane frag reads are 256B
// contiguous -> 2-way bank aliasing only (free). Reg-staged (16B loads).
// EPI: 0 = bias, store bf16 (QKV, proj)
//      2 = bias + exact GELU, store bf16 (FFN1)
//      3 = bias + resid(f32 chunk-local), store f32 (FFN2)
// ---------------------------------------------------------------------------
template<int EPI>
__global__ __launch_bounds__(256) void gemm_mfma(
    const bf16* __restrict__ A, const bf16* __restrict__ WT,
    const float* __restrict__ bias, void* __restrict__ Cout,
    const float* __restrict__ resid, int Mrows, int N, int K)
{
    __shared__ short As[4][128][8];   // 8 KB
    __shared__ short Bs[4][128][8];   // 8 KB
    int tid = threadIdx.x, lane = tid & 63, wid = tid >> 6;
    int wm = wid >> 1, wn = wid & 1;
    int row0 = blockIdx.x * 128, col0 = blockIdx.y * 128;

    f32x4 acc[4][4] = {};

    const char* Ab = (const char*)A;
    const char* Bb = (const char*)WT;
    const int K2 = K * 2;
    const int o0 = tid * 16, o1 = 4096 + tid * 16;   // LDS byte chunks per thread

    for (int kt = 0; kt < K; kt += 32) {
        short8 va0, va1, vb0, vb1;
        {
            int hi = o0 >> 11, m = (o0 >> 4) & 127;
            int rowA = row0 + m; if (rowA >= Mrows) rowA = Mrows - 1;
            va0 = *(const short8*)(Ab + (size_t)rowA * K2 + kt * 2 + hi * 16);
            vb0 = *(const short8*)(Bb + (size_t)(col0 + m) * K2 + kt * 2 + hi * 16);
        }
        {
            int hi = o1 >> 11, m = (o1 >> 4) & 127;
            int rowA = row0 + m; if (rowA >= Mrows) rowA = Mrows - 1;
            va1 = *(const short8*)(Ab + (size_t)rowA * K2 + kt * 2 + hi * 16);
            vb1 = *(const short8*)(Bb + (size_t)(col0 + m) * K2 + kt * 2 + hi * 16);
        }
        __syncthreads();   // prior iteration's LDS reads complete
        *(short8*)((char*)As + o0) = va0;
        *(short8*)((char*)Bs + o0) = vb0;
        *(short8*)((char*)As + o1) = va1;
        *(short8*)((char*)Bs + o1) = vb1;
        __syncthreads();

        const int hi = lane >> 4, l15 = lane & 15;
        short8 af[4], bfr[4];
#pragma unroll
        for (int t4 = 0; t4 < 4; ++t4) {
            af[t4]  = *(const short8*)&As[hi][wm * 64 + t4 * 16 + l15][0];
            bfr[t4] = *(const short8*)&Bs[hi][wn * 64 + t4 * 16 + l15][0];
        }
#pragma unroll
        for (int mt = 0; mt < 4; ++mt)
#pragma unroll
            for (int nt = 0; nt < 4; ++nt)
                acc[mt][nt] = __builtin_amdgcn_mfma_f32_16x16x32_bf16(
                    af[mt], bfr[nt], acc[mt][nt], 0, 0, 0);
    }

    const int l15 = lane & 15, lq = lane >> 4;
#pragma unroll
    for (int mt = 0; mt < 4; ++mt) {
        int rbase = row0 + wm * 64 + mt * 16 + lq * 4;
#pragma unroll
        for (int nt = 0; nt < 4; ++nt) {
            int c = col0 + wn * 64 + nt * 16 + l15;
            float bz = bias[c];
            f32x4 v = acc[mt][nt];
#pragma unroll
            for (int rg = 0; rg < 4; ++rg) {
                int r = rbase + rg;
                if (r < Mrows) {
                    float val = v[rg] + bz;
                    if (EPI == 0) {
                        ((bf16*)Cout)[(size_t)r * N + c] = __float2bfloat16(val);
                    } else if (EPI == 2) {
                        float gl = 0.5f * val * (1.f + erff(val * 0.70710678118654752f));
                        ((bf16*)Cout)[(size_t)r * N + c] = __float2bfloat16(gl);
                    } else {
                        ((float*)Cout)[(size_t)r * N + c] =
                            resid[(size_t)r * N + c] + val;
                    }
                }
            }
        }
    }
}

// ---------------------------------------------------------------------------
// Attention: one block per (window, head). qkv bf16 [tok][384], out bf16.
// ---------------------------------------------------------------------------
__global__ __launch_bounds__(256) void attn_kernel(
    const bf16* __restrict__ qkv, const float* __restrict__ rpb,
    bf16* __restrict__ out, int shifted)
{
    __shared__ float qs[49 * 33];
    __shared__ float ks[49 * 33];
    __shared__ float vs[49 * 33];
    __shared__ float Ss[49 * 50];

    int win = blockIdx.x >> 2;
    int h   = blockIdx.x & 3;
    int tid = threadIdx.x;
    int whh = (win & 63) >> 3, www = win & 7;

    for (int idx = tid; idx < 196; idx += 256) {    // 49 rows x 4 chunks of 8
        int n = idx >> 2, c = idx & 3;
        const short8* bp = (const short8*)(qkv + (size_t)(win * 49 + n) * 384 + h * 32 + c * 8);
        short8 vq = bp[0], vk = bp[16], vv = bp[32];
#pragma unroll
        for (int j = 0; j < 8; ++j) {
            qs[n * 33 + c * 8 + j] = bf2f(vq[j]) * 0.17677669529663687f;
            ks[n * 33 + c * 8 + j] = bf2f(vk[j]);
            vs[n * 33 + c * 8 + j] = bf2f(vv[j]);
        }
    }
    __syncthreads();

    for (int idx = tid; idx < 49 * 49; idx += 256) {
        int i = idx / 49, j = idx - i * 49;
        float s = 0.f;
#pragma unroll 8
        for (int d = 0; d < 32; ++d) s += qs[i * 33 + d] * ks[j * 33 + d];
        int ih = i / 7, iw = i - ih * 7, jh = j / 7, jw = j - jh * 7;
        int ridx = (ih - jh + 6) * 13 + (iw - jw + 6);
        s += rpb[ridx * 4 + h];
        if (shifted) {
            int yi = whh * 7 + ih, xi = www * 7 + iw;
            int yj = whh * 7 + jh, xj = www * 7 + jw;
            int ci = (yi < 49 ? 0 : (yi < 53 ? 1 : 2)) * 3 + (xi < 49 ? 0 : (xi < 53 ? 1 : 2));
            int cj = (yj < 49 ? 0 : (yj < 53 ? 1 : 2)) * 3 + (xj < 49 ? 0 : (xj < 53 ? 1 : 2));
            if (ci != cj) s -= 100.f;
        }
        Ss[i * 50 + j] = s;
    }
    __syncthreads();

    if (tid < 49) {
        float m = -1e30f;
        for (int j = 0; j < 49; ++j) m = fmaxf(m, Ss[tid * 50 + j]);
        float sum = 0.f;
        for (int j = 0; j < 49; ++j) {
            float e = expf(Ss[tid * 50 + j] - m);
            Ss[tid * 50 + j] = e;
            sum += e;
        }
        float inv = 1.f / sum;
        for (int j = 0; j < 49; ++j) Ss[tid * 50 + j] *= inv;
    }
    __syncthreads();

    for (int idx = tid; idx < 49 * 32; idx += 256) {
        int i = idx >> 5, d = idx & 31;
        float s = 0.f;
#pragma unroll 7
        for (int j = 0; j < 49; ++j) s += Ss[i * 50 + j] * vs[j * 33 + d];
        out[(size_t)(win * 49 + i) * CC + h * 32 + d] = __float2bfloat16(s);
    }
}

// ---------------------------------------------------------------------------
extern "C" void kernel_launch(void* const* d_in, const int* in_sizes, int n_in,
                              void* d_out, int out_size, void* d_ws, size_t ws_size,
                              hipStream_t stream)
{
    const float* x    = (const float*)d_in[0];
    const float* n1g  = (const float*)d_in[1];
    const float* n1b  = (const float*)d_in[2];
    const float* qkvw = (const float*)d_in[3];
    const float* qkvb = (const float*)d_in[4];
    const float* rpb  = (const float*)d_in[5];
    const float* pw   = (const float*)d_in[6];
    const float* pb   = (const float*)d_in[7];
    const float* n2g  = (const float*)d_in[8];
    const float* n2b  = (const float*)d_in[9];
    const float* f1w  = (const float*)d_in[10];
    const float* f1b  = (const float*)d_in[11];
    const float* f2w  = (const float*)d_in[12];
    const float* f2b  = (const float*)d_in[13];
    float* out = (float*)d_out;

    // ---- workspace layout ----
    char* ws = (char*)d_ws;
    bf16* wqkvT = (bf16*)ws;                                   // 2*49152
    bf16* wpT   = (bf16*)(ws + 196608);                        // 2*16384
    bf16* wf1T  = (bf16*)(ws + 196608 + 65536);                // 2*65536
    bf16* wf2T  = (bf16*)(ws + 196608 + 65536 + 262144);       // 2*65536
    const size_t WOFF = 786432;

    // per-image activation bytes: bufAb(bf16)+projw(bf16)+bigb(bf16)+x1c(f32)
    // = 3136 * (256 + 256 + 1024 + 512) = 3136 * 2048
    const size_t PER_IMG = (size_t)3136 * 2048;
    int ipc = 1;
    for (int cand = 8; cand >= 1; cand >>= 1) {
        if (WOFF + (size_t)cand * PER_IMG <= ws_size) { ipc = cand; break; }
    }
    const int MCd = ipc * 3136;
    const int nchunk = 32 / ipc;
    const int gx = (MCd + 127) / 128;

    char* p = ws + WOFF;
    bf16* bufAb = (bf16*)p;  p += (size_t)MCd * 128 * 2;   // ln1/attn/ln2 outputs
    bf16* projw = (bf16*)p;  p += (size_t)MCd * 128 * 2;   // proj output (windowed)
    bf16* bigb  = (bf16*)p;  p += (size_t)MCd * 512 * 2;   // qkv (384) / ffn hidden (512)
    float* x1c  = (float*)p;                                // post-attn residual f32

    // ---- weight prep (once per launch; ws is re-poisoned every call) ----
    for (int i = 0; i < 2; ++i) {
        transposeW<<<192, 256, 0, stream>>>(qkvw + i * 49152, wqkvT + i * 49152, 128, 384);
        transposeW<<<64,  256, 0, stream>>>(pw   + i * 16384, wpT   + i * 16384, 128, 128);
        transposeW<<<256, 256, 0, stream>>>(f1w  + i * 65536, wf1T  + i * 65536, 128, 512);
        transposeW<<<256, 256, 0, stream>>>(f2w  + i * 65536, wf2T  + i * 65536, 512, 128);
    }

    const float* xin = x;
    for (int i = 0; i < 2; ++i) {
        int shift = i ? 3 : 0;
        for (int c = 0; c < nchunk; ++c) {
            int R0 = c * MCd;
            // LN1 + shift + window partition -> bf16 windowed
            ln1_kernel<<<MCd / 4, 256, 0, stream>>>(xin, n1g + i * 128, n1b + i * 128,
                                                    bufAb, shift, R0);
            // QKV: [MCd,128] @ [128,384]
            gemm_mfma<0><<<dim3(gx, 3), 256, 0, stream>>>(bufAb, wqkvT + i * 49152,
                qkvb + i * 384, bigb, nullptr, MCd, 384, 128);
            // attention (bf16 in/out, windowed)
            attn_kernel<<<(MCd / 49) * 4, 256, 0, stream>>>(bigb, rpb + i * 676, bufAb, i);
            // proj: [MCd,128] @ [128,128] -> windowed bf16 (bias only)
            gemm_mfma<0><<<dim3(gx, 1), 256, 0, stream>>>(bufAb, wpT + i * 16384,
                pb + i * 128, projw, nullptr, MCd, 128, 128);
            // fused: window-reverse + roll-back + residual + LN2
            ln2_fused<<<MCd / 4, 256, 0, stream>>>(projw, xin, n2g + i * 128, n2b + i * 128,
                                                   x1c, bufAb, shift, R0);
            // FFN1 + GELU: [MCd,128] @ [128,512] -> bf16
            gemm_mfma<2><<<dim3(gx, 4), 256, 0, stream>>>(bufAb, wf1T + i * 65536,
                f1b + i * 512, bigb, nullptr, MCd, 512, 128);
            // FFN2 + residual: [MCd,512] @ [512,128] -> f32 out slice
            gemm_mfma<3><<<dim3(gx, 1), 256, 0, stream>>>(bigb, wf2T + i * 65536,
                f2b + i * 128, out + (size_t)R0 * CC, x1c, MCd, 128, 512);
        }
        xin = out;
    }
    (void)in_sizes; (void)n_in; (void)out_size;
}